// Round 2
// baseline (19647.522 us; speedup 1.0000x reference)
//
#include <hip/hip_runtime.h>
#include <math.h>

#define B_   16
#define S_   64
#define V_   32000
#define D_   1024
#define W_   4
#define BW   64          // B*W rows
#define L_   75          // min(int(1.1*64+5), 512)
#define EOS_ 2
#define NEGF (-1e9f)
#define BN   128
#define NB   (V_/BN)     // 250 column-tile blocks

// ---------- top-4 helpers (jax.lax.top_k semantics: desc value, asc index on ties) ----------
__device__ __forceinline__ bool better(float v1, int i1, float v2, int i2) {
    return (v1 > v2) || (v1 == v2 && i1 < i2);
}
__device__ __forceinline__ void ins4(float v, int ix, float tv[4], int ti[4]) {
    if (!better(v, ix, tv[3], ti[3])) return;
    tv[3] = v; ti[3] = ix;
    #pragma unroll
    for (int j = 3; j > 0; --j) {
        if (better(tv[j], ti[j], tv[j-1], ti[j-1])) {
            float fv = tv[j]; tv[j] = tv[j-1]; tv[j-1] = fv;
            int   iv = ti[j]; ti[j] = ti[j-1]; ti[j-1] = iv;
        }
    }
}

// ---------- encoder context: masked mean of (emb[token] + lang_emb[src_lang]) ----------
__global__ void k_ctx(const int* __restrict__ src, const int* __restrict__ sizes,
                      const int* __restrict__ slang, const float* __restrict__ emb,
                      const float* __restrict__ lemb, float* __restrict__ ctx) {
    const int b = blockIdx.x >> 2;
    const int d = ((blockIdx.x & 3) << 8) + threadIdx.x;
    const int n = sizes[b];
    const float lv = lemb[slang[b]*D_ + d];
    const int* sp = src + b*S_;
    float acc = 0.f;
    for (int s = 0; s < S_; ++s) {
        if (s < n) acc += emb[sp[s]*D_ + d] + lv;   // ref order: (emb + lang) summed over s
    }
    ctx[b*D_ + d] = acc / (float)n;
}

// ---------- state init ----------
__global__ void k_init(const int* __restrict__ sizes, const int* __restrict__ ft,
                       float* __restrict__ scores, int* __restrict__ last, int* __restrict__ fe,
                       int* __restrict__ mlens, int* __restrict__ done, int* __restrict__ T0) {
    const int t = threadIdx.x;
    if (t < BW) {
        scores[t] = ((t & 3) == 0) ? 0.f : NEGF;   // step-1 trick: only beam 0 alive
        last[t]   = ft[t >> 2];
        fe[t]     = -1;                             // first-eos position, -1 = none
    }
    if (t < B_) mlens[t] = min((int)(1.1f * (float)sizes[t] + 5.0f), 512);
    if (t == 0) *done = 0;
    for (int e = t; e < BW * L_; e += 256) {
        int r = e / L_, c = e - r * L_;
        T0[e] = (c == 0) ? ft[r >> 2] : 0;
    }
}

// ---------- initial h (step 1): hT[d*64+r] = tanh((emb[last]+ctx)+lang) ----------
__global__ void k_h0(const int* __restrict__ last, const float* __restrict__ emb,
                     const float* __restrict__ ctx, const float* __restrict__ lemb,
                     const int* __restrict__ tlang, float* __restrict__ hT) {
    for (int j = 0; j < 4; ++j) {
        int e = j * 16384 + blockIdx.x * 256 + threadIdx.x;   // e = d*64 + r
        int r = e & 63, d = e >> 6, b = r >> 2;
        hT[e] = tanhf((emb[last[r]*D_ + d] + ctx[b*D_ + d]) + lemb[tlang[b]*D_ + d]);
    }
}

// ---------- per-step GEMM: z = h @ W, with per-(block,row) partial max / sumexp / top-4 ----------
// grid NB=250, block 512 (8 waves). Wave w owns rows 8w..8w+7; lane owns 2 columns.
// readfirstlane makes the h address provably wave-uniform -> scalar (SMEM) loads,
// freeing VMEM issue slots and letting v_fma take h as the single SGPR operand.
__global__ __launch_bounds__(512) void k_gemm(const float* __restrict__ hT, const float* __restrict__ w,
        float* __restrict__ pmax, float* __restrict__ psum,
        float* __restrict__ pval, int* __restrict__ pidx, const int* __restrict__ done) {
    if (*done) return;
    const int tid  = threadIdx.x;
    const int wv   = __builtin_amdgcn_readfirstlane(tid >> 6);  // wave id, SGPR-uniform
    const int lane = tid & 63;
    const int c    = blockIdx.x * BN + lane * 2;
    const int r0   = wv << 3;
    const float* wp = w  + c;
    const float* hp = hT + r0;
    float acc[8][2];
    #pragma unroll
    for (int rr = 0; rr < 8; ++rr) { acc[rr][0] = 0.f; acc[rr][1] = 0.f; }
    #pragma unroll 4
    for (int k = 0; k < D_; ++k) {
        const float2 w2 = *(const float2*)wp;
        const float4 ha = *(const float4*)hp;
        const float4 hb = *(const float4*)(hp + 4);
        wp += V_; hp += 64;
        const float hr[8] = {ha.x, ha.y, ha.z, ha.w, hb.x, hb.y, hb.z, hb.w};
        #pragma unroll
        for (int rr = 0; rr < 8; ++rr) {
            acc[rr][0] = fmaf(hr[rr], w2.x, acc[rr][0]);
            acc[rr][1] = fmaf(hr[rr], w2.y, acc[rr][1]);
        }
    }
    // per-row wave reduction: running (max, sumexp) + top-4 (value desc, idx asc)
    for (int rr = 0; rr < 8; ++rr) {
        const float v0 = acc[rr][0], v1 = acc[rr][1];
        float m = fmaxf(v0, v1);
        float s = expf(v0 - m) + expf(v1 - m);
        float tv[4]; int ti[4];
        const bool f = better(v0, c, v1, c + 1);
        tv[0] = f ? v0 : v1;  ti[0] = f ? c : c + 1;
        tv[1] = f ? v1 : v0;  ti[1] = f ? c + 1 : c;
        tv[2] = tv[3] = -3.4e38f;  ti[2] = ti[3] = 0x7fffffff;
        #pragma unroll
        for (int off = 1; off < 64; off <<= 1) {
            const float om = __shfl_xor(m, off), os = __shfl_xor(s, off);
            float ov[4]; int oi[4];
            #pragma unroll
            for (int j = 0; j < 4; ++j) { ov[j] = __shfl_xor(tv[j], off); oi[j] = __shfl_xor(ti[j], off); }
            const float nm = fmaxf(m, om);
            s = s * expf(m - nm) + os * expf(om - nm);
            m = nm;
            #pragma unroll
            for (int j = 0; j < 4; ++j) ins4(ov[j], oi[j], tv, ti);
        }
        if (lane == 0) {
            const int o = blockIdx.x * 64 + r0 + rr;
            pmax[o] = m; psum[o] = s;
            #pragma unroll
            for (int j = 0; j < 4; ++j) { pval[o*4 + j] = tv[j]; pidx[o*4 + j] = ti[j]; }
        }
    }
}

// ---------- per-step merge + softmax/penalty + batch top-4 + beam update + next h ----------
__global__ __launch_bounds__(1024) void k_update(
        int i, const int* __restrict__ srcT, int* __restrict__ dstT,
        const float* __restrict__ pmax, const float* __restrict__ psum,
        const float* __restrict__ pval, const int* __restrict__ pidx,
        float* __restrict__ scores, int* __restrict__ last, int* __restrict__ fe,
        const int* __restrict__ mlens, int* __restrict__ done,
        const float* __restrict__ emb, const float* __restrict__ ctx,
        const float* __restrict__ lemb, const int* __restrict__ tlang,
        float* __restrict__ hT) {
    __shared__ float rv[64][4];
    __shared__ int   ri[64][4];
    __shared__ float rM[64], rL[64];
    __shared__ int   sfe[64], sbeam[64], sword[64], slast[64];
    __shared__ int   s_alive;
    const int t = threadIdx.x;
    if (t == 0) s_alive = 0;
    __syncthreads();

    // ---- phase A: merge 250 per-block partials into per-row (max, lse, top-4) ----
    {
        const int r = t >> 4, part = t & 15;
        float m = -3.4e38f, s = 0.f;
        float tv[4]; int ti[4];
        #pragma unroll
        for (int j = 0; j < 4; ++j) { tv[j] = -3.4e38f; ti[j] = 0x7fffffff; }
        for (int blk = part; blk < NB; blk += 16) {
            const int o = blk * 64 + r;
            const float pm = pmax[o], ps = psum[o];
            const float nm = fmaxf(m, pm);
            s = s * expf(m - nm) + ps * expf(pm - nm);
            m = nm;
            #pragma unroll
            for (int j = 0; j < 4; ++j) ins4(pval[o*4 + j], pidx[o*4 + j], tv, ti);
        }
        #pragma unroll
        for (int off = 1; off < 16; off <<= 1) {
            const float om = __shfl_xor(m, off), os = __shfl_xor(s, off);
            float ov[4]; int oi[4];
            #pragma unroll
            for (int j = 0; j < 4; ++j) { ov[j] = __shfl_xor(tv[j], off); oi[j] = __shfl_xor(ti[j], off); }
            const float nm = fmaxf(m, om);
            s = s * expf(m - nm) + os * expf(om - nm);
            m = nm;
            #pragma unroll
            for (int j = 0; j < 4; ++j) ins4(ov[j], oi[j], tv, ti);
        }
        if (part == 0) {
            rM[r] = m; rL[r] = logf(s);
            #pragma unroll
            for (int j = 0; j < 4; ++j) { rv[r][j] = tv[j]; ri[r][j] = ti[j]; }
        }
    }
    if (t < 64) { const int f = fe[t]; sfe[t] = f; if (f < 0) s_alive = 1; }
    __syncthreads();
    const int all_done = (s_alive == 0);

    // ---- phase B: per-batch top-4 over 4 rows x 4 candidates, then state update ----
    if (t < B_) {
        const int b = t;
        if (all_done) {
            #pragma unroll
            for (int k = 0; k < 4; ++k) slast[b*4 + k] = last[b*4 + k];
            if (b == 0) *done = 1;
        } else {
            const bool reached = (mlens[b] <= i);          // max_lens < i+1
            const bool r2 = reached && (i > 1);
            float bv[4]; int bi[4];
            #pragma unroll
            for (int j = 0; j < 4; ++j) { bv[j] = -3.4e38f; bi[j] = 0x7fffffff; }
            #pragma unroll
            for (int w = 0; w < 4; ++w) {
                const int rr = b*4 + w;
                const float sc = scores[rr];
                const int f = sfe[rr];
                const bool eos = (f >= 0);
                const bool zero = eos || r2;
                const float len = eos ? (float)(f + 6) : (float)(i + 5);
                const float pen = powf(len / 6.0f, 0.8f);
                if (zero) {
                    const float v = (sc + 0.0f) / pen;      // logp forced to 0 for whole row
                    #pragma unroll
                    for (int j = 0; j < 4; ++j) ins4(v, w*V_ + j, bv, bi);
                } else {
                    const float M = rM[rr], Lg = rL[rr];
                    #pragma unroll
                    for (int j = 0; j < 4; ++j) {
                        const float sh = rv[rr][j] - M;     // ref op order: (z - max) - log(sum)
                        const float lp = sh - Lg;
                        ins4((sc + lp) / pen, w*V_ + ri[rr][j], bv, bi);
                    }
                }
            }
            #pragma unroll
            for (int k = 0; k < 4; ++k) {
                const int idx = r2 ? 0 : bi[k];             // reached -> pad_idx
                const int bm = idx / V_, wd = idx - bm * V_;
                const int rr = b*4 + k;
                scores[rr] = bv[k];                          // top_scores kept even when reached
                slast[rr]  = wd;  last[rr] = wd;
                sbeam[rr]  = bm;  sword[rr] = wd;
                const int of = sfe[b*4 + bm];
                fe[rr] = (of >= 0) ? of : ((wd == EOS_) ? i : -1);
            }
        }
    }
    __syncthreads();

    // ---- token reshuffle + append ----
    for (int e = t; e < BW * L_; e += 1024) {
        const int rr = e / L_, c = e - rr * L_;
        const int sr = all_done ? rr : ((rr & ~3) | sbeam[rr]);
        int v = srcT[sr * L_ + c];
        if (!all_done && c == i) v = sword[rr];
        dstT[e] = v;
    }
    // ---- phase C: h for next step ----
    for (int e = t; e < BW * D_; e += 1024) {
        const int rr = e & 63, d = e >> 6, b = rr >> 2;
        hT[e] = tanhf((emb[slast[rr]*D_ + d] + ctx[b*D_ + d]) + lemb[tlang[b]*D_ + d]);
    }
}

// ---------- output: tokens[:,0,:] as float, then scores ----------
__global__ void k_out(const int* __restrict__ T, const float* __restrict__ scores,
                      float* __restrict__ out) {
    const int t = blockIdx.x * 256 + threadIdx.x;
    if (t < B_ * L_) {
        const int b = t / L_, p = t - b * L_;
        out[t] = (float)T[(b * 4) * L_ + p];
    } else if (t < B_ * L_ + BW) {
        out[t] = scores[t - B_ * L_];
    }
}

extern "C" void kernel_launch(void* const* d_in, const int* in_sizes, int n_in,
                              void* d_out, int out_size, void* d_ws, size_t ws_size,
                              hipStream_t stream) {
    const int*   src   = (const int*)d_in[0];
    const int*   sizes = (const int*)d_in[1];
    const int*   ft    = (const int*)d_in[2];
    // d_in[3] = src_mask: redundant with src_sizes, unused
    const int*   slang = (const int*)d_in[4];
    const int*   tlang = (const int*)d_in[5];
    // d_in[6] = pad_idx (always 0)
    const float* emb   = (const float*)d_in[7];
    const float* lemb  = (const float*)d_in[8];
    const float* w     = (const float*)d_in[9];

    char* ws = (char*)d_ws;
    float* ctx    = (float*)(ws + 0);        // 16*1024*4      = 65536
    float* hT     = (float*)(ws + 65536);    // 1024*64*4      = 262144
    int*   T0     = (int*)  (ws + 327680);   // 64*75*4        = 19200
    int*   T1     = (int*)  (ws + 346880);   // 19200
    float* scores = (float*)(ws + 366080);
    int*   last   = (int*)  (ws + 366336);
    int*   fe     = (int*)  (ws + 366592);
    int*   mlens  = (int*)  (ws + 366848);
    int*   done   = (int*)  (ws + 367104);
    float* pmax   = (float*)(ws + 367360);   // 250*64*4       = 64000
    float* psum   = (float*)(ws + 431360);   // 64000
    float* pval   = (float*)(ws + 495360);   // 250*64*4*4     = 256000
    int*   pidx   = (int*)  (ws + 751360);   // 256000 -> end 1007360 bytes

    k_ctx <<<64, 256, 0, stream>>>(src, sizes, slang, emb, lemb, ctx);
    k_init<<<1, 256, 0, stream>>>(sizes, ft, scores, last, fe, mlens, done, T0);
    k_h0  <<<64, 256, 0, stream>>>(last, emb, ctx, lemb, tlang, hT);

    for (int i = 1; i < L_; ++i) {
        k_gemm<<<NB, 512, 0, stream>>>(hT, w, pmax, psum, pval, pidx, done);
        const int* sT = (i & 1) ? T0 : T1;
        int*       dT = (i & 1) ? T1 : T0;
        k_update<<<1, 1024, 0, stream>>>(i, sT, dT, pmax, psum, pval, pidx,
                                         scores, last, fe, mlens, done,
                                         emb, ctx, lemb, tlang, hT);
    }
    // 74 steps (even count) -> final tokens land back in T0
    k_out<<<5, 256, 0, stream>>>(T0, scores, (float*)d_out);
}